// Round 8
// baseline (71.066 us; speedup 1.0000x reference)
//
#include <hip/hip_runtime.h>

#define B_ 2
#define Q_ 2048
#define K_ 2048
#define H_ 16
#define D_ 64
#define HD_ (H_ * D_)

// Q pre-scale: (1/sqrt(64)) * log2(e)  -> scores in log2 units; softmax uses
// raw v_exp_f32 (2^x) with no per-element multiply.
#define QSCALE 0.18033688011112042f
#define DEFER_THR 10.0f   // log2-units; P bounded by 2^10, fine in bf16/f32

typedef __bf16 bf16_t;
typedef __attribute__((ext_vector_type(8))) __bf16 bf16x8;
typedef __attribute__((ext_vector_type(4))) __bf16 bf16x4;
typedef __attribute__((ext_vector_type(4))) float f32x4;

// Raw barrier: drains LDS ops only; global register-prefetch stays in flight.
#define SBAR() do {                                         \
    __builtin_amdgcn_sched_barrier(0);                      \
    asm volatile("s_waitcnt lgkmcnt(0)" ::: "memory");      \
    __builtin_amdgcn_s_barrier();                           \
    __builtin_amdgcn_sched_barrier(0);                      \
} while (0)

// Swizzled byte offset for a [N][64] bf16 tile (row stride 128 B).
// XOR bits 4-6 with row&7: bijective, keeps 16B granules, kills bank conflicts.
__device__ __forceinline__ int swz(int row, int colByte) {
    return (row * 128 + colByte) ^ ((row & 7) << 4);
}

__global__ __launch_bounds__(256, 4) void attn_fwd_kernel(
    const float* __restrict__ qs, const float* __restrict__ ks,
    const float* __restrict__ vs, const int* __restrict__ valid_lens,
    float* __restrict__ out)
{
    const int qt   = blockIdx.x;   // 64-row q tile
    const int h    = blockIdx.y;
    const int b    = blockIdx.z;
    const int tid  = threadIdx.x;
    const int wave = tid >> 6;     // 0..3, each owns 16 q rows
    const int lane = tid & 63;
    const int l16  = lane & 15;
    const int lhi  = lane >> 4;    // 0..3

    const int valid  = valid_lens[b];
    const int ntiles = (valid + 63) >> 6;   // tiles fully past valid contribute exactly 0

    __shared__ bf16_t k_lds[2][64 * 64];    // [buf][key][d], swizzled
    __shared__ bf16_t v_lds[2][64 * 64];    // [buf][d][key] transposed, swizzled
    __shared__ bf16_t p_buf[4][16 * 64];    // per-wave P tile, swizzled
    char* const pbase = (char*)&p_buf[wave][0];

    // ---- Q fragment (lane = row l16, k-dim d = dh*32+lhi*8+j), scale folded.
    // Used as the B-operand of the swapped QK^T.
    const int    qrow = qt * 64 + wave * 16 + l16;
    const float* qp   = qs + (((size_t)b * Q_ + qrow) * H_ + h) * D_;
    bf16x8 a_q[2];
    #pragma unroll
    for (int dh = 0; dh < 2; ++dh) {
        const f32x4* q4 = (const f32x4*)(qp + dh * 32 + lhi * 8);
        f32x4 lo = q4[0], hi = q4[1];
        #pragma unroll
        for (int j = 0; j < 4; ++j) {
            a_q[dh][j]     = (bf16_t)(lo[j] * QSCALE);
            a_q[dh][4 + j] = (bf16_t)(hi[j] * QSCALE);
        }
    }

    // O accumulator: C-layout of swapped PV -> lane holds q-row = l16,
    // d = t*16 + lhi*4 + r. Softmax state is per-lane scalars.
    f32x4 o_acc[4];
    #pragma unroll
    for (int t = 0; t < 4; ++t) o_acc[t] = (f32x4){0.f, 0.f, 0.f, 0.f};
    float m_r = -1e30f, l_part = 0.f;

    const float* kb = ks + ((size_t)b * K_ * H_ + h) * D_;
    const float* vg = vs + ((size_t)b * K_ * H_ + h) * D_;

    // staging role split (wave-uniform): waves 0-1 stage K, waves 2-3 stage V
    const bool kRole = (tid < 128);
    const int  st    = kRole ? tid : (tid - 128);   // 0..127
    const int  krow  = st >> 1;                     // 0..63 (key)
    const int  kcolf = (st & 1) * 32;               // float col base (32 floats/thread)
    const int  vr    = (st & 15) * 4;               // key base (4 rows)
    const int  vc    = (st >> 4) * 8;               // d base (8 cols)

    f32x4 reg[8];   // in-flight next tile (lives across the barrier)

    auto issue_loads = [&](int kt) {
        if (kRole) {
            const float* ksrc = kb + (size_t)(kt * 64 + krow) * HD_ + kcolf;
            #pragma unroll
            for (int i = 0; i < 8; ++i) reg[i] = ((const f32x4*)ksrc)[i];
        } else {
            #pragma unroll
            for (int i = 0; i < 4; ++i) {
                const float* vsrc = vg + (size_t)(kt * 64 + vr + i) * HD_ + vc;
                reg[2 * i]     = ((const f32x4*)vsrc)[0];
                reg[2 * i + 1] = ((const f32x4*)vsrc)[1];
            }
        }
    };

    auto write_tile = [&](int bi) {
        if (kRole) {
            char* kdst = (char*)&k_lds[bi][0];
            #pragma unroll
            for (int p = 0; p < 4; ++p) {
                bf16x8 w;
                #pragma unroll
                for (int j = 0; j < 4; ++j) {
                    w[j]     = (bf16_t)reg[2 * p][j];
                    w[4 + j] = (bf16_t)reg[2 * p + 1][j];
                }
                *(bf16x8*)(kdst + swz(krow, kcolf * 2 + p * 16)) = w;
            }
        } else {
            char* vdst = (char*)&v_lds[bi][0];
            #pragma unroll
            for (int j = 0; j < 4; ++j) {
                bf16x4 w;
                #pragma unroll
                for (int r = 0; r < 4; ++r) w[r] = (bf16_t)reg[2 * r][j];
                *(bf16x4*)(vdst + swz(vc + j, vr * 2)) = w;
            }
            #pragma unroll
            for (int j = 0; j < 4; ++j) {
                bf16x4 w;
                #pragma unroll
                for (int r = 0; r < 4; ++r) w[r] = (bf16_t)reg[2 * r + 1][j];
                *(bf16x4*)(vdst + swz(vc + 4 + j, vr * 2)) = w;
            }
        }
    };

    // prologue: tile 0 straight to LDS
    issue_loads(0);
    write_tile(0);
    int cur = 0;

    for (int kt = 0; kt < ntiles; ++kt) {
        const bool more = (kt + 1 < ntiles);
        if (more) issue_loads(kt + 1);   // stays in flight across SBAR (no vmcnt drain)
        SBAR();                          // buf[cur] ds_writes visible; readers of buf[cur^1] done

        char* const kbase = (char*)&k_lds[cur][0];
        char* const vbase = (char*)&v_lds[cur][0];

        // ---- S^T = K Q^T (swapped operands): lane holds q-row l16,
        // keys n*16 + lhi*4 + r across s[n][r].
        f32x4 s[4];
        #pragma unroll
        for (int n = 0; n < 4; ++n) s[n] = (f32x4){0.f, 0.f, 0.f, 0.f};
        __builtin_amdgcn_s_setprio(1);
        #pragma unroll
        for (int n = 0; n < 4; ++n) {
            #pragma unroll
            for (int dh = 0; dh < 2; ++dh) {
                bf16x8 ak = *(const bf16x8*)(kbase + swz(n * 16 + l16, dh * 64 + lhi * 16));
                s[n] = __builtin_amdgcn_mfma_f32_16x16x32_bf16(ak, a_q[dh], s[n], 0, 0, 0);
            }
        }
        __builtin_amdgcn_s_setprio(0);

        // ---- mask only on the boundary tile (uniform branch) ----
        if (kt * 64 + 64 > valid) {
            #pragma unroll
            for (int n = 0; n < 4; ++n) {
                const int kbase_i = kt * 64 + n * 16 + lhi * 4;
                #pragma unroll
                for (int r = 0; r < 4; ++r)
                    if (kbase_i + r >= valid) s[n][r] = -1e30f;
            }
        }

        // ---- deferred-max online softmax, all state lane-local ----
        float lm = s[0][0];
        #pragma unroll
        for (int n = 0; n < 4; ++n)
            #pragma unroll
            for (int r = 0; r < 4; ++r) lm = fmaxf(lm, s[n][r]);
        if (__any(lm > m_r + DEFER_THR)) {   // rare, wave-uniform update
            float rm = fmaxf(lm, __shfl_xor(lm, 16, 64));
            rm = fmaxf(rm, __shfl_xor(rm, 32, 64));
            const float mnew  = fmaxf(m_r, rm);
            const float alpha = __builtin_amdgcn_exp2f(m_r - mnew);
            m_r = mnew;
            l_part *= alpha;
            #pragma unroll
            for (int t = 0; t < 4; ++t) o_acc[t] *= alpha;
        }
        // P = 2^(s-m); 4 consecutive keys per n -> b64 LDS writes
        float psum = 0.f;
        #pragma unroll
        for (int n = 0; n < 4; ++n) {
            bf16x4 w;
            #pragma unroll
            for (int r = 0; r < 4; ++r) {
                const float e = __builtin_amdgcn_exp2f(s[n][r] - m_r);
                psum += e;
                w[r] = (bf16_t)e;
            }
            *(bf16x4*)(pbase + swz(l16, n * 32 + lhi * 8)) = w;
        }
        l_part += psum;

        // B-fragments of P: lane = q-col l16, k = keys kk*32 + lhi*8 + j
        bf16x8 pb[2];
        #pragma unroll
        for (int kk = 0; kk < 2; ++kk)
            pb[kk] = *(const bf16x8*)(pbase + swz(l16, kk * 64 + lhi * 16));

        // ---- PV swapped: O^T = V^T P^T -> lane = q-col, d-rows ----
        __builtin_amdgcn_s_setprio(1);
        #pragma unroll
        for (int t = 0; t < 4; ++t) {
            #pragma unroll
            for (int kk = 0; kk < 2; ++kk) {
                bf16x8 vb = *(const bf16x8*)(vbase + swz(t * 16 + l16, kk * 64 + lhi * 16));
                o_acc[t] = __builtin_amdgcn_mfma_f32_16x16x32_bf16(vb, pb[kk], o_acc[t], 0, 0, 0);
            }
        }
        __builtin_amdgcn_s_setprio(0);

        // regs -> LDS for next tile; vmcnt paid HERE (after full compute phase)
        if (more) write_tile(cur ^ 1);
        cur ^= 1;
    }

    // ---- epilogue: finish l over the lhi group, divide, vector store ----
    float l = l_part;
    l += __shfl_xor(l, 16, 64);
    l += __shfl_xor(l, 32, 64);
    const float inv = 1.f / l;
    float* op = out + (((size_t)b * Q_ + qrow) * H_ + h) * D_;
    #pragma unroll
    for (int t = 0; t < 4; ++t) {
        f32x4 res = o_acc[t];
        #pragma unroll
        for (int r = 0; r < 4; ++r) res[r] *= inv;
        *(f32x4*)(op + t * 16 + lhi * 4) = res;
    }
}

extern "C" void kernel_launch(void* const* d_in, const int* in_sizes, int n_in,
                              void* d_out, int out_size, void* d_ws, size_t ws_size,
                              hipStream_t stream) {
    const float* qs = (const float*)d_in[0];
    const float* ks = (const float*)d_in[1];
    const float* vs = (const float*)d_in[2];
    const int*   vl = (const int*)d_in[3];
    float*       out = (float*)d_out;
    dim3 grid(Q_ / 64, H_, B_);
    attn_fwd_kernel<<<grid, 256, 0, stream>>>(qs, ks, vs, vl, out);
}